// Round 11
// baseline (3012.999 us; speedup 1.0000x reference)
//
#include <hip/hip_runtime.h>
#include <math.h>

// Problem constants (fixed by the reference)
constexpr int N_ = 101, H_ = 128;
constexpr int SK = 129;              // padded LDS stride for K table
constexpr float EPS_ = 1e-5f;

// LDS layout (float words) — 14,360 words = 57,440 B (< 64 KiB)
constexpr int OFF_KH  = 0;                    // 13032: K table (also Kp staging)
constexpr int OFF_AT  = 13032;                // 816: attention weights (8 heads x 101)
constexpr int OFF_DRAW = OFF_AT + 816;        // 128: raw decoder vector (16B aligned)
constexpr int OFF_XV  = OFF_DRAW + 128;       // 128: x = attn@V   (16B aligned)
constexpr int OFF_YR  = OFF_XV + 128;         // 128: raw y = x@wo (16B aligned)
constexpr int OFF_CP  = OFF_YR + 128;         // 128: comp
constexpr int LDS_WORDS = OFF_CP + 128;

#define WSUM(v) { v += __shfl_xor(v,1,64); v += __shfl_xor(v,2,64); v += __shfl_xor(v,4,64); \
                  v += __shfl_xor(v,8,64); v += __shfl_xor(v,16,64); v += __shfl_xor(v,32,64); }
#define WMAX(v) { v = fmaxf(v,__shfl_xor(v,1,64)); v = fmaxf(v,__shfl_xor(v,2,64)); \
                  v = fmaxf(v,__shfl_xor(v,4,64)); v = fmaxf(v,__shfl_xor(v,8,64)); \
                  v = fmaxf(v,__shfl_xor(v,16,64)); v = fmaxf(v,__shfl_xor(v,32,64)); }

__device__ __forceinline__ float rdlane(float v, int l) {
  return __int_as_float(__builtin_amdgcn_readlane(__float_as_int(v), l));
}

__global__ __launch_bounds__(512, 2) void gat_decoder(
    const float* __restrict__ enc, const float* __restrict__ pool,
    const float* __restrict__ capac, const float* __restrict__ dem,
    const float* __restrict__ fcw, const float* __restrict__ fc1w,
    const float* __restrict__ lng, const float* __restrict__ lnb,
    const float* __restrict__ wq, const float* __restrict__ wk,
    const float* __restrict__ wvm, const float* __restrict__ wo,
    const float* __restrict__ kpw, const float* __restrict__ plg,
    const float* __restrict__ plb, const int* __restrict__ tp,
    float* __restrict__ out, int Bv, int ns)
{
  __shared__ float sm[LDS_WORDS];
  const int tid  = threadIdx.x;
  const int b    = blockIdx.x;
  const int lane = tid & 63;
  const int wvid = tid >> 6;        // wave id 0..7 (= head id)
  const int lc   = lane & 15;       // local column
  const int sl   = lane >> 4;       // k-slice 0..3 within wave
  const int col  = wvid * 16 + lc;  // output column owned by this thread
  const int n1 = lane, n2 = lane + 64;

  const float NEG_INF = -__builtin_inff();
  int ti = tp[0];
  float Tf = (ti > 1000000 || ti < -1000000) ? __int_as_float((int)ti) : (float)ti;
  const float inv_sqrt_h = 1.0f / sqrtf(128.0f);
  const float PSUM_CONST = 1.0f + (float)N_ * 1e-10f;

  const float* encb = enc + (size_t)b * (N_ * H_);

  float* KH  = sm + OFF_KH;  float* AT = sm + OFF_AT;
  float* DRAW = sm + OFF_DRAW;
  float* XV = sm + OFF_XV;   float* YR = sm + OFF_YR;
  float* CP = sm + OFF_CP;

  // ---------- (a) Kp col-layout into KH staging (wave-uniform enc reads) ----------
  {
    const int j3 = tid & 127;
    const int g3 = __builtin_amdgcn_readfirstlane(tid >> 7);
    const int r03 = g3 * 26, nr3 = (g3 == 3) ? 23 : 26;
    float acc[26];
    #pragma unroll
    for (int t = 0; t < 26; ++t) acc[t] = 0.f;
    for (int k0 = 0; k0 < H_; k0 += 8) {
      float w8[8];
      #pragma unroll
      for (int kk = 0; kk < 8; ++kk) w8[kk] = kpw[(k0 + kk) * H_ + j3];
      #pragma unroll
      for (int t = 0; t < 26; ++t) if (t < nr3) {
        const float* ep = encb + (r03 + t) * H_ + k0;
        #pragma unroll
        for (int kk = 0; kk < 8; ++kk) acc[t] = fmaf(ep[kk], w8[kk], acc[t]);
      }
    }
    #pragma unroll
    for (int t = 0; t < 26; ++t) if (t < nr3) KH[(r03 + t) * SK + j3] = acc[t];
  }
  __syncthreads();
  // ---------- (c) transposed Kp registers + pointer-LN fold ----------
  // kpT[r] = Kp[col][sl*32+r] * plg[sl*32+r];  kps = sum_j Kp*plg;  cpb = sum_j Kp*plb
  float kpT[32], kps, cpb;
  {
    const int neff = (col < N_) ? col : (N_ - 1);
    const float* src = KH + neff * SK + sl * 32;
    float ks = 0.f, cb = 0.f;
    #pragma unroll
    for (int r = 0; r < 32; ++r) {
      const float kv = src[r];
      const float pg = plg[sl * 32 + r];
      const float pb2 = plb[sl * 32 + r];
      ks = fmaf(kv, pg, ks);
      cb = fmaf(kv, pb2, cb);
      kpT[r] = kv * pg;
    }
    ks += __shfl_xor(ks, 16, 64); ks += __shfl_xor(ks, 32, 64);
    cb += __shfl_xor(cb, 16, 64); cb += __shfl_xor(cb, 32, 64);
    kps = ks; cpb = cb;
  }
  __syncthreads();
  // ---------- (e) K col-layout into KH ----------
  {
    const int j3 = tid & 127;
    const int g3 = __builtin_amdgcn_readfirstlane(tid >> 7);
    const int r03 = g3 * 26, nr3 = (g3 == 3) ? 23 : 26;
    float acc[26];
    #pragma unroll
    for (int t = 0; t < 26; ++t) acc[t] = 0.f;
    for (int k0 = 0; k0 < H_; k0 += 8) {
      float w8[8];
      #pragma unroll
      for (int kk = 0; kk < 8; ++kk) w8[kk] = wk[(k0 + kk) * H_ + j3];
      #pragma unroll
      for (int t = 0; t < 26; ++t) if (t < nr3) {
        const float* ep = encb + (r03 + t) * H_ + k0;
        #pragma unroll
        for (int kk = 0; kk < 8; ++kk) acc[t] = fmaf(ep[kk], w8[kk], acc[t]);
      }
    }
    #pragma unroll
    for (int t = 0; t < 26; ++t) if (t < nr3) KH[(r03 + t) * SK + j3] = acc[t];
  }
  // ---------- (f) V col-slices: vh[t] = V[sl*26+t][col] ----------
  float vh[26];
  {
    const int r0v = sl * 26, nrv = (sl == 3) ? 23 : 26;
    #pragma unroll
    for (int t = 0; t < 26; ++t) vh[t] = 0.f;
    for (int k0 = 0; k0 < H_; k0 += 8) {
      float w8[8];
      #pragma unroll
      for (int kk = 0; kk < 8; ++kk) w8[kk] = wvm[(k0 + kk) * H_ + col];
      #pragma unroll
      for (int t = 0; t < 26; ++t) if (t < nrv) {
        const float* ep = encb + (r0v + t) * H_ + k0;   // uniform within 16-lane group
        #pragma unroll
        for (int kk = 0; kk < 8; ++kk) vh[t] = fmaf(ep[kk], w8[kk], vh[t]);
      }
    }
  }
  // ---------- weights (fc, wo plain; wq folded with decoder-LN) ----------
  float fc_r[32], wo_r[32], wq_r[32], wqs, qb;
  {
    float ws = 0.f, bsum = 0.f;
    #pragma unroll
    for (int r = 0; r < 32; ++r) {
      fc_r[r] = fcw[(sl * 32 + r) * H_ + col];
      wo_r[r] = wo[(sl * 32 + r) * H_ + col];
      const float w = wq[(sl * 32 + r) * H_ + col];
      const float lg = lng[sl * 32 + r];
      const float lb = lnb[sl * 32 + r];
      wq_r[r] = w * lg;
      ws = fmaf(w, lg, ws);
      bsum = fmaf(w, lb, bsum);
    }
    ws += __shfl_xor(ws, 16, 64); ws += __shfl_xor(ws, 32, 64);
    bsum += __shfl_xor(bsum, 16, 64); bsum += __shfl_xor(bsum, 32, 64);
    wqs = ws; qb = bsum;
  }
  const float fcap = fcw[128 * H_ + col];
  // pool_proc[col]
  float pp;
  {
    const float* pb = pool + (size_t)b * H_;
    float p = 0.f;
    #pragma unroll
    for (int r = 0; r < 32; ++r) p = fmaf(pb[sl * 32 + r], fc1w[(sl * 32 + r) * H_ + col], p);
    p += __shfl_xor(p, 16, 64); p += __shfl_xor(p, 32, 64);
    pp = p;
  }
  // ---------- per-wave redundant decode state ----------
  const float capv = capac[b];
  float cap = capv, lpsum = 0.f;
  float demA = dem[(size_t)b * N_ + n1];
  float demC = (n2 < N_) ? dem[(size_t)b * N_ + n2] : 0.f;
  int vis = 0, pidx = 0;
  bool m1a = false, m1c = false, mbA, mbB;
  {
    bool infA = (n1 >= 1) && (demA > cap);
    bool infB = (n2 >= N_) || (demC > cap);
    bool feasA = (n1 >= 1) && !infA;
    bool feasB = (n2 < N_) && !infB;
    const bool anyf = __any(feasA || feasB);
    mbA = (n1 == 0) ? anyf : infA;
    mbB = infB;
  }
  __syncthreads();   // K table + everything ready

  // ---------- decode loop: 4 barriers/step ----------
  for (int i = 0; i < ns; ++i) {
    const int pu = __builtin_amdgcn_readfirstlane(pidx);

    // B: draw[col] = enc[pidx] @ fc_w + cap*fcap + pp   (in-wave reduce)
    {
      const float* ep = encb + (size_t)pu * H_ + sl * 32;
      float p = 0.f;
      #pragma unroll
      for (int r = 0; r < 32; ++r) p = fmaf(fc_r[r], ep[r], p);
      p += __shfl_xor(p, 16, 64); p += __shfl_xor(p, 32, 64);
      p += cap * fcap + pp;
      if (sl == 0) DRAW[col] = p;
    }
    __syncthreads();                                            // bar1

    // Q: per-wave LN stats (from DRAW) || folded matvec -> q; logits; softmax; X
    {
      // stats — redundant per wave, overlaps with the dot below
      const float DA = DRAW[n1], DC = DRAW[n2 & 127];
      float s1 = DA + DC;
      WSUM(s1);
      const float mu = s1 * (1.f / 128.f);
      const float da = DA - mu, dc = DC - mu;
      float vv = da * da + dc * dc;
      WSUM(vv);
      const float inv = 1.0f / sqrtf(vv * (1.f / 128.f) + EPS_);
      // dot(wq', draw) (b128 reads)
      const float4* dv4 = (const float4*)(DRAW + sl * 32);
      float p = 0.f;
      #pragma unroll
      for (int r4 = 0; r4 < 8; ++r4) {
        const float4 u = dv4[r4];
        p = fmaf(wq_r[r4 * 4 + 0], u.x, p);
        p = fmaf(wq_r[r4 * 4 + 1], u.y, p);
        p = fmaf(wq_r[r4 * 4 + 2], u.z, p);
        p = fmaf(wq_r[r4 * 4 + 3], u.w, p);
      }
      p += __shfl_xor(p, 16, 64); p += __shfl_xor(p, 32, 64);
      const float q = inv * (p - mu * wqs) + qb;   // folded LayerNorm
      // logits (wave = head), qd via readlane
      const float* k1 = KH + n1 * SK + wvid * 16;
      const float* k2 = KH + ((n2 < N_) ? n2 : n1) * SK + wvid * 16;
      float a1 = 0.f, a2r = 0.f;
      #pragma unroll
      for (int d = 0; d < 16; ++d) {
        const float qdv = rdlane(q, d);
        a1  = fmaf(qdv, k1[d], a1);
        a2r = fmaf(qdv, k2[d], a2r);
      }
      a1 = mbA ? NEG_INF : a1 * 0.25f;
      float a2 = (n2 < N_ && !mbB) ? a2r * 0.25f : NEG_INF;
      float mx = fmaxf(a1, a2);
      WMAX(mx);
      float e1 = expf(a1 - mx);
      float e2 = (n2 < N_) ? expf(a2 - mx) : 0.f;
      float ss = e1 + e2;
      WSUM(ss);
      AT[wvid * N_ + n1] = e1 / ss;
      if (n2 < N_) AT[wvid * N_ + n2] = e2 / ss;
      // X: x[col] = attn(head wvid) @ V — same-wave AT reads (no barrier)
      const float* aw = AT + wvid * N_ + sl * 26;
      const int nrv = (sl == 3) ? 23 : 26;
      float x = 0.f;
      #pragma unroll
      for (int t = 0; t < 26; ++t) if (t < nrv) x = fmaf(aw[t], vh[t], x);
      x += __shfl_xor(x, 16, 64); x += __shfl_xor(x, 32, 64);
      if (sl == 0) XV[col] = x;
    }
    __syncthreads();                                            // bar2

    // Y: y[col] = x @ wo (b128 reads, in-wave reduce)
    {
      const float4* xp4 = (const float4*)(XV + sl * 32);
      float y = 0.f;
      #pragma unroll
      for (int r4 = 0; r4 < 8; ++r4) {
        const float4 u = xp4[r4];
        y = fmaf(wo_r[r4 * 4 + 0], u.x, y);
        y = fmaf(wo_r[r4 * 4 + 1], u.y, y);
        y = fmaf(wo_r[r4 * 4 + 2], u.z, y);
        y = fmaf(wo_r[r4 * 4 + 3], u.w, y);
      }
      y += __shfl_xor(y, 16, 64); y += __shfl_xor(y, 32, 64);
      if (sl == 0) YR[col] = y;
    }
    __syncthreads();                                            // bar3

    // C: per-wave LN stats (from YR) || folded matvec with kpT' -> comp
    {
      const float YA = YR[n1], YC = YR[n2 & 127];
      float s1 = YA + YC;
      WSUM(s1);
      const float mu = s1 * (1.f / 128.f);
      const float da = YA - mu, dc = YC - mu;
      float vv = da * da + dc * dc;
      WSUM(vv);
      const float inv = 1.0f / sqrtf(vv * (1.f / 128.f) + EPS_);
      const float4* yp4 = (const float4*)(YR + sl * 32);
      float c = 0.f;
      #pragma unroll
      for (int r4 = 0; r4 < 8; ++r4) {
        const float4 u = yp4[r4];
        c = fmaf(kpT[r4 * 4 + 0], u.x, c);
        c = fmaf(kpT[r4 * 4 + 1], u.y, c);
        c = fmaf(kpT[r4 * 4 + 2], u.z, c);
        c = fmaf(kpT[r4 * 4 + 3], u.w, c);
      }
      c += __shfl_xor(c, 16, 64); c += __shfl_xor(c, 32, 64);
      const float comp = inv * (c - mu * kps) + cpb;   // folded pointer-LN
      if (sl == 0 && col < N_) CP[col] = comp;
    }
    __syncthreads();                                            // bar4

    // AM — all waves redundantly: argmax, lp, state, next masks (registers)
    {
      const bool allmb = __all(mbA && mbB);
      float c1 = mbA ? NEG_INF : CP[n1] * inv_sqrt_h / Tf;
      float c2 = (n2 < N_ && !mbB) ? CP[n2 & 127] * inv_sqrt_h / Tf : NEG_INF;
      if (allmb) { c1 = 0.f; c2 = (n2 < N_) ? 0.f : NEG_INF; }
      float bv = c1; int bi = n1;
      if (c2 > bv) { bv = c2; bi = n2; }
      #pragma unroll
      for (int o = 32; o; o >>= 1) {
        float ov = __shfl_xor(bv, o, 64);
        int   oi = __shfl_xor(bi, o, 64);
        if (ov > bv || (ov == bv && oi < bi)) { bv = ov; bi = oi; }
      }
      float e1 = expf(c1 - bv);
      float e2 = (n2 < N_) ? expf(c2 - bv) : 0.f;
      float ss = e1 + e2;
      WSUM(ss);
      float lp = logf((1.0f / ss + 1e-10f) / PSUM_CONST);
      if (vis >= N_ - 1) lp = 0.f;
      lpsum += lp;
      const int bis = __builtin_amdgcn_readfirstlane(bi);
      const float dsel = (bis < 64) ? rdlane(demA, bis) : rdlane(demC, bis - 64);
      cap = (bis == 0) ? capv : (cap - dsel);
      if (bis != 0) {
        const bool newly = ((bis == n1) && !m1a) || ((bis == n2) && !m1c);
        if (__any(newly)) vis += 1;
        m1a = m1a || (bis == n1);
        m1c = m1c || (bis == n2);
      }
      bool infA = (n1 >= 1) && (m1a || demA > cap);
      bool infB = (n2 >= N_) || m1c || (demC > cap);
      bool feasA = (n1 >= 1) && !infA;
      bool feasB = (n2 < N_) && !infB;
      const bool anyf = __any(feasA || feasB);
      const bool depot_m = anyf && (bis == 0);
      mbA = (n1 == 0) ? depot_m : infA;
      mbB = infB;
      pidx = bis;
      if (wvid == 0 && lane == 0) out[(size_t)b * (ns + 2) + 1 + i] = (float)bis;
    }
    // hazard check: next DRAW write is >=3 barriers past this iter's last DRAW read. safe.
  }

  if (wvid == 0 && lane == 0) {
    out[(size_t)b * (ns + 2)] = 0.f;
    out[(size_t)b * (ns + 2) + ns + 1] = (pidx == 0) ? -1.f : 0.f;
    out[(size_t)Bv * (ns + 2) + b] = lpsum;   // log_p
  }
}

extern "C" void kernel_launch(void* const* d_in, const int* in_sizes, int n_in,
                              void* d_out, int out_size, void* d_ws, size_t ws_size,
                              hipStream_t stream) {
  const int Bv = in_sizes[0] / (N_ * H_);   // 1024
  const int ns = out_size / Bv - 3;         // B*(ns+2) actions + B log_p => 120
  gat_decoder<<<dim3(Bv), dim3(512), 0, stream>>>(
      (const float*)d_in[0],  (const float*)d_in[1],  (const float*)d_in[2],
      (const float*)d_in[3],  (const float*)d_in[4],  (const float*)d_in[5],
      (const float*)d_in[6],  (const float*)d_in[7],  (const float*)d_in[8],
      (const float*)d_in[9],  (const float*)d_in[10], (const float*)d_in[11],
      (const float*)d_in[12], (const float*)d_in[13], (const float*)d_in[14],
      (const int*)d_in[16],
      (float*)d_out, Bv, ns);
}

// Round 12
// 2903.456 us; speedup vs baseline: 1.0377x; 1.0377x over previous
//
#include <hip/hip_runtime.h>
#include <math.h>

// Problem constants (fixed by the reference)
constexpr int N_ = 101, H_ = 128;
constexpr int SKE = 132;             // table stride, 16B-aligned rows
constexpr float EPS_ = 1e-5f;

// LDS layout (float words) — 14,660 words = 58,640 B (< 64 KiB)
constexpr int OFF_TAB = 0;                    // 101*132 = 13332: Kp/K staging, then EF table
constexpr int OFF_AT  = N_ * SKE;             // 816: attn weights (8 heads x 101); setup: pool partials
constexpr int OFF_FC  = OFF_AT + 816;         // 128: fcw capacity row
constexpr int OFF_XV  = OFF_FC + 128;         // 128: x = attn@V
constexpr int OFF_YR  = OFF_XV + 128;         // 128: raw y = x@wo
constexpr int OFF_CP  = OFF_YR + 128;         // 128: comp (setup: pool_proc vector)
constexpr int LDS_WORDS = OFF_CP + 128;

__device__ __forceinline__ float rdlane(float v, int l) {
  return __int_as_float(__builtin_amdgcn_readlane(__float_as_int(v), l));
}

// DPP reductions (VALU, ~8cy/hop vs ~120cy ds_bpermute)
template<int CTRL, int RM>
__device__ __forceinline__ float dppadd(float x) {
  int v = __builtin_amdgcn_update_dpp(0, __float_as_int(x), CTRL, RM, 0xf, true);
  return x + __int_as_float(v);
}
template<int CTRL, int RM>
__device__ __forceinline__ float dppmax(float x) {
  int v = __builtin_amdgcn_update_dpp(__float_as_int(x), __float_as_int(x), CTRL, RM, 0xf, false);
  return fmaxf(x, __int_as_float(v));
}
__device__ __forceinline__ float wave_sum(float x) {   // rocPRIM wave64 sequence
  x = dppadd<0x111,0xf>(x);  // row_shr:1
  x = dppadd<0x112,0xf>(x);  // row_shr:2
  x = dppadd<0x114,0xf>(x);  // row_shr:4
  x = dppadd<0x118,0xf>(x);  // row_shr:8
  x = dppadd<0x142,0xa>(x);  // row_bcast:15 -> rows 1,3
  x = dppadd<0x143,0xc>(x);  // row_bcast:31 -> rows 2,3
  return rdlane(x, 63);
}
__device__ __forceinline__ float wave_max(float x) {
  x = dppmax<0x111,0xf>(x); x = dppmax<0x112,0xf>(x);
  x = dppmax<0x114,0xf>(x); x = dppmax<0x118,0xf>(x);
  x = dppmax<0x142,0xa>(x); x = dppmax<0x143,0xc>(x);
  return rdlane(x, 63);
}
__device__ __forceinline__ float grp4_sum(float x) {   // sum of lanes 4c..4c+3, valid at lane 4c+3
  x = dppadd<0x111,0xf>(x);
  x = dppadd<0x112,0xf>(x);
  return x;
}

__global__ __launch_bounds__(512, 2) void gat_decoder(
    const float* __restrict__ enc, const float* __restrict__ pool,
    const float* __restrict__ capac, const float* __restrict__ dem,
    const float* __restrict__ fcw, const float* __restrict__ fc1w,
    const float* __restrict__ lng, const float* __restrict__ lnb,
    const float* __restrict__ wq, const float* __restrict__ wk,
    const float* __restrict__ wvm, const float* __restrict__ wo,
    const float* __restrict__ kpw, const float* __restrict__ plg,
    const float* __restrict__ plb, const int* __restrict__ tp,
    float* __restrict__ out, int Bv, int ns)
{
  __shared__ float sm[LDS_WORDS];
  const int tid  = threadIdx.x;
  const int b    = blockIdx.x;
  const int lane = tid & 63;
  const int wvid = tid >> 6;        // wave id 0..7 (= head id)
  const int sl   = lane & 3;        // k-slice 0..3 (ADJACENT lanes -> 2-hop DPP slice sum)
  const int lc   = lane >> 2;       // local column 0..15
  const int col  = wvid * 16 + lc;  // output column owned by this thread
  const int n1 = lane, n2 = lane + 64;

  const float NEG_INF = -__builtin_inff();
  int ti = tp[0];
  float Tf = (ti > 1000000 || ti < -1000000) ? __int_as_float((int)ti) : (float)ti;
  const float inv_sqrt_h = 1.0f / sqrtf(128.0f);
  const float PSUM_CONST = 1.0f + (float)N_ * 1e-10f;

  const float* encb = enc + (size_t)b * (N_ * H_);

  float* TAB = sm + OFF_TAB;  float* AT = sm + OFF_AT;
  float* FC  = sm + OFF_FC;   float* XV = sm + OFF_XV;
  float* YR  = sm + OFF_YR;   float* CP = sm + OFF_CP;

  const int j3 = tid & 127;                                 // staging column
  const int g3 = __builtin_amdgcn_readfirstlane(tid >> 7);  // staging row group
  const int r03 = g3 * 26, nr3 = (g3 == 3) ? 23 : 26;

  // ---------- stage 0: pool partials -> AT; FC fill ----------
  {
    const float* pb = pool + (size_t)b * H_;
    float p = 0.f;
    #pragma unroll
    for (int r = 0; r < 32; ++r) p = fmaf(pb[g3 * 32 + r], fc1w[(g3 * 32 + r) * H_ + j3], p);
    AT[g3 * 128 + j3] = p;
    if (tid < 128) FC[tid] = fcw[128 * H_ + tid];
  }
  __syncthreads();
  if (tid < 128) CP[tid] = AT[tid] + AT[128 + tid] + AT[256 + tid] + AT[384 + tid];  // pool_proc

  // ---------- stage 1: Kp into TAB ----------
  {
    float acc[26];
    #pragma unroll
    for (int t = 0; t < 26; ++t) acc[t] = 0.f;
    for (int k0 = 0; k0 < H_; k0 += 8) {
      float w8[8];
      #pragma unroll
      for (int kk = 0; kk < 8; ++kk) w8[kk] = kpw[(k0 + kk) * H_ + j3];
      #pragma unroll
      for (int t = 0; t < 26; ++t) if (t < nr3) {
        const float* ep = encb + (r03 + t) * H_ + k0;
        #pragma unroll
        for (int kk = 0; kk < 8; ++kk) acc[t] = fmaf(ep[kk], w8[kk], acc[t]);
      }
    }
    #pragma unroll
    for (int t = 0; t < 26; ++t) if (t < nr3) TAB[(r03 + t) * SKE + j3] = acc[t];
  }
  __syncthreads();

  // ---------- kpT regs + pointer-LN fold (kps, cpb valid at lane 4c+3) ----------
  float kpT[32], kps, cpb;
  {
    const int neff = (col < N_) ? col : (N_ - 1);
    const float* src = TAB + neff * SKE + sl * 32;
    float ks = 0.f, cb = 0.f;
    #pragma unroll
    for (int r = 0; r < 32; ++r) {
      const float kv = src[r];
      const float pg = plg[sl * 32 + r];
      const float pb2 = plb[sl * 32 + r];
      ks = fmaf(kv, pg, ks);
      cb = fmaf(kv, pb2, cb);
      kpT[r] = kv * pg;
    }
    kps = grp4_sum(ks); cpb = grp4_sum(cb);
  }
  __syncthreads();

  // ---------- stage 2: K into TAB ----------
  {
    float acc[26];
    #pragma unroll
    for (int t = 0; t < 26; ++t) acc[t] = 0.f;
    for (int k0 = 0; k0 < H_; k0 += 8) {
      float w8[8];
      #pragma unroll
      for (int kk = 0; kk < 8; ++kk) w8[kk] = wk[(k0 + kk) * H_ + j3];
      #pragma unroll
      for (int t = 0; t < 26; ++t) if (t < nr3) {
        const float* ep = encb + (r03 + t) * H_ + k0;
        #pragma unroll
        for (int kk = 0; kk < 8; ++kk) acc[t] = fmaf(ep[kk], w8[kk], acc[t]);
      }
    }
    #pragma unroll
    for (int t = 0; t < 26; ++t) if (t < nr3) TAB[(r03 + t) * SKE + j3] = acc[t];
  }
  __syncthreads();

  // ---------- K into per-lane registers: khA[d]=K[n1][wvid*16+d], khB for n2 ----------
  float khA[16], khB[16];
  {
    const int row2 = (n2 < N_) ? n2 : n1;
    const float* s1 = TAB + n1 * SKE + wvid * 16;
    const float* s2 = TAB + row2 * SKE + wvid * 16;
    #pragma unroll
    for (int d = 0; d < 16; ++d) { khA[d] = s1[d]; khB[d] = s2[d]; }
  }
  __syncthreads();

  // ---------- stage 3: EF' = enc@fc_w + pool_proc into TAB ----------
  {
    const float pcj = CP[j3];
    float acc[26];
    #pragma unroll
    for (int t = 0; t < 26; ++t) acc[t] = pcj;
    for (int k0 = 0; k0 < H_; k0 += 8) {
      float w8[8];
      #pragma unroll
      for (int kk = 0; kk < 8; ++kk) w8[kk] = fcw[(k0 + kk) * H_ + j3];
      #pragma unroll
      for (int t = 0; t < 26; ++t) if (t < nr3) {
        const float* ep = encb + (r03 + t) * H_ + k0;
        #pragma unroll
        for (int kk = 0; kk < 8; ++kk) acc[t] = fmaf(ep[kk], w8[kk], acc[t]);
      }
    }
    #pragma unroll
    for (int t = 0; t < 26; ++t) if (t < nr3) TAB[(r03 + t) * SKE + j3] = acc[t];
  }

  // ---------- V col-slices: vh[t] = V[sl*26+t][col] ----------
  float vh[26];
  {
    const int r0v = sl * 26, nrv = (sl == 3) ? 23 : 26;
    #pragma unroll
    for (int t = 0; t < 26; ++t) vh[t] = 0.f;
    for (int k0 = 0; k0 < H_; k0 += 8) {
      float w8[8];
      #pragma unroll
      for (int kk = 0; kk < 8; ++kk) w8[kk] = wvm[(k0 + kk) * H_ + col];
      #pragma unroll
      for (int t = 0; t < 26; ++t) if (t < nrv) {
        const float* ep = encb + (r0v + t) * H_ + k0;
        #pragma unroll
        for (int kk = 0; kk < 8; ++kk) vh[t] = fmaf(ep[kk], w8[kk], vh[t]);
      }
    }
  }
  // ---------- wq folded with decoder-LN; wo plain; wfc = wq'@FC_col ----------
  float wq_r[32], wo_r[32], wqs, qb, wfc;
  {
    float ws = 0.f, bsum = 0.f, wf = 0.f;
    #pragma unroll
    for (int r = 0; r < 32; ++r) {
      wo_r[r] = wo[(sl * 32 + r) * H_ + col];
      const float w = wq[(sl * 32 + r) * H_ + col];
      const float lg = lng[sl * 32 + r];
      const float lb = lnb[sl * 32 + r];
      const float wp = w * lg;
      wq_r[r] = wp;
      ws += wp;
      bsum = fmaf(w, lb, bsum);
      wf = fmaf(wp, fcw[128 * H_ + sl * 32 + r], wf);
    }
    wqs = grp4_sum(ws); qb = grp4_sum(bsum); wfc = grp4_sum(wf);
  }
  // ---------- per-wave redundant decode state ----------
  const float capv = capac[b];
  float cap = capv, lpsum = 0.f;
  float demA = dem[(size_t)b * N_ + n1];
  float demC = (n2 < N_) ? dem[(size_t)b * N_ + n2] : 0.f;
  int vis = 0, pidx = 0;
  bool m1a = false, m1c = false, mbA, mbB;
  {
    bool infA = (n1 >= 1) && (demA > cap);
    bool infB = (n2 >= N_) || (demC > cap);
    bool feasA = (n1 >= 1) && !infA;
    bool feasB = (n2 < N_) && !infB;
    const bool anyf = __any(feasA || feasB);
    mbA = (n1 == 0) ? anyf : infA;
    mbB = infB;
  }
  __syncthreads();   // EF table + everything ready

  // ---------- decode loop: 3 barriers/step, no global loads ----------
  for (int i = 0; i < ns; ++i) {
    const int pu = __builtin_amdgcn_readfirstlane(pidx);
    const float* EROW = TAB + pu * SKE;

    // Q: LN stats (DPP) || folded q-matvec from EF row; logits(reg K); softmax; X
    {
      const float DA = EROW[n1] + cap * FC[n1];
      const float DC = EROW[n2 & 127] + cap * FC[n2 & 127];
      const float mu = wave_sum(DA + DC) * (1.f / 128.f);
      const float da = DA - mu, dc = DC - mu;
      const float inv = 1.0f / sqrtf(wave_sum(da * da + dc * dc) * (1.f / 128.f) + EPS_);
      // dot(wq', EF_row) chunk (b128 LDS reads)
      const float4* e4 = (const float4*)(EROW + sl * 32);
      float p = 0.f;
      #pragma unroll
      for (int r4 = 0; r4 < 8; ++r4) {
        const float4 u = e4[r4];
        p = fmaf(wq_r[r4 * 4 + 0], u.x, p);
        p = fmaf(wq_r[r4 * 4 + 1], u.y, p);
        p = fmaf(wq_r[r4 * 4 + 2], u.z, p);
        p = fmaf(wq_r[r4 * 4 + 3], u.w, p);
      }
      p = grp4_sum(p);                                   // valid at lane 4c+3
      const float q = inv * ((p + cap * wfc) - mu * wqs) + qb;   // folded LN
      // logits from register K; q broadcast via readlane (col c at lane 4c+3)
      float a1 = 0.f, a2r = 0.f;
      #pragma unroll
      for (int d = 0; d < 16; ++d) {
        const float qdv = rdlane(q, 4 * d + 3);
        a1  = fmaf(qdv, khA[d], a1);
        a2r = fmaf(qdv, khB[d], a2r);
      }
      a1 = mbA ? NEG_INF : a1 * 0.25f;
      float a2 = (n2 < N_ && !mbB) ? a2r * 0.25f : NEG_INF;
      const float mx = wave_max(fmaxf(a1, a2));
      float e1 = expf(a1 - mx);
      float e2 = (n2 < N_) ? expf(a2 - mx) : 0.f;
      const float ss = wave_sum(e1 + e2);
      AT[wvid * N_ + n1] = e1 / ss;
      if (n2 < N_) AT[wvid * N_ + n2] = e2 / ss;
      // X: x[col] = attn(head wvid) @ V — same-wave AT reads
      const float* aw = AT + wvid * N_ + sl * 26;
      const int nrv = (sl == 3) ? 23 : 26;
      float x = 0.f;
      #pragma unroll
      for (int t = 0; t < 26; ++t) if (t < nrv) x = fmaf(aw[t], vh[t], x);
      x = grp4_sum(x);
      if (sl == 3) XV[col] = x;
    }
    __syncthreads();                                            // bar1

    // Y: y[col] = x @ wo
    {
      const float4* xp4 = (const float4*)(XV + sl * 32);
      float y = 0.f;
      #pragma unroll
      for (int r4 = 0; r4 < 8; ++r4) {
        const float4 u = xp4[r4];
        y = fmaf(wo_r[r4 * 4 + 0], u.x, y);
        y = fmaf(wo_r[r4 * 4 + 1], u.y, y);
        y = fmaf(wo_r[r4 * 4 + 2], u.z, y);
        y = fmaf(wo_r[r4 * 4 + 3], u.w, y);
      }
      y = grp4_sum(y);
      if (sl == 3) YR[col] = y;
    }
    __syncthreads();                                            // bar2

    // C: LN stats (DPP) || folded comp-matvec with kpT'
    {
      const float YA = YR[n1], YC = YR[n2 & 127];
      const float mu = wave_sum(YA + YC) * (1.f / 128.f);
      const float da = YA - mu, dc = YC - mu;
      const float inv = 1.0f / sqrtf(wave_sum(da * da + dc * dc) * (1.f / 128.f) + EPS_);
      const float4* yp4 = (const float4*)(YR + sl * 32);
      float c = 0.f;
      #pragma unroll
      for (int r4 = 0; r4 < 8; ++r4) {
        const float4 u = yp4[r4];
        c = fmaf(kpT[r4 * 4 + 0], u.x, c);
        c = fmaf(kpT[r4 * 4 + 1], u.y, c);
        c = fmaf(kpT[r4 * 4 + 2], u.z, c);
        c = fmaf(kpT[r4 * 4 + 3], u.w, c);
      }
      c = grp4_sum(c);
      const float comp = inv * (c - mu * kps) + cpb;   // folded pointer-LN
      if (sl == 3 && col < N_) CP[col] = comp;
    }
    __syncthreads();                                            // bar3

    // AM — all waves redundantly: DPP max + ballot argmax, lp, state, masks
    {
      const bool allmb = __all(mbA && mbB);
      float c1 = mbA ? NEG_INF : CP[n1] * inv_sqrt_h / Tf;
      float c2 = (n2 < N_ && !mbB) ? CP[n2 & 127] * inv_sqrt_h / Tf : NEG_INF;
      if (allmb) { c1 = 0.f; c2 = (n2 < N_) ? 0.f : NEG_INF; }
      const float mx = wave_max(fmaxf(c1, c2));
      const unsigned long long b1 = __ballot(c1 == mx);
      const unsigned long long b2 = __ballot(c2 == mx);
      const int bis = b1 ? (__ffsll((long long)b1) - 1)
                         : (64 + __ffsll((long long)b2) - 1);
      float e1 = expf(c1 - mx);
      float e2 = (n2 < N_) ? expf(c2 - mx) : 0.f;
      const float ss = wave_sum(e1 + e2);
      float lp = logf((1.0f / ss + 1e-10f) / PSUM_CONST);
      if (vis >= N_ - 1) lp = 0.f;
      lpsum += lp;
      const float dsel = (bis < 64) ? rdlane(demA, bis) : rdlane(demC, bis - 64);
      cap = (bis == 0) ? capv : (cap - dsel);
      if (bis != 0) {
        const bool newly = ((bis == n1) && !m1a) || ((bis == n2) && !m1c);
        if (__any(newly)) vis += 1;
        m1a = m1a || (bis == n1);
        m1c = m1c || (bis == n2);
      }
      bool infA = (n1 >= 1) && (m1a || demA > cap);
      bool infB = (n2 >= N_) || m1c || (demC > cap);
      bool feasA = (n1 >= 1) && !infA;
      bool feasB = (n2 < N_) && !infB;
      const bool anyf = __any(feasA || feasB);
      const bool depot_m = anyf && (bis == 0);
      mbA = (n1 == 0) ? depot_m : infA;
      mbB = infB;
      pidx = bis;
      if (wvid == 0 && lane == 0) out[(size_t)b * (ns + 2) + 1 + i] = (float)bis;
    }
    // hazards: next Q writes AT (same-wave only) and XV (last read in Y, 2 barriers back). safe.
  }

  if (wvid == 0 && lane == 0) {
    out[(size_t)b * (ns + 2)] = 0.f;
    out[(size_t)b * (ns + 2) + ns + 1] = (pidx == 0) ? -1.f : 0.f;
    out[(size_t)Bv * (ns + 2) + b] = lpsum;   // log_p
  }
}

extern "C" void kernel_launch(void* const* d_in, const int* in_sizes, int n_in,
                              void* d_out, int out_size, void* d_ws, size_t ws_size,
                              hipStream_t stream) {
  const int Bv = in_sizes[0] / (N_ * H_);   // 1024
  const int ns = out_size / Bv - 3;         // B*(ns+2) actions + B log_p => 120
  gat_decoder<<<dim3(Bv), dim3(512), 0, stream>>>(
      (const float*)d_in[0],  (const float*)d_in[1],  (const float*)d_in[2],
      (const float*)d_in[3],  (const float*)d_in[4],  (const float*)d_in[5],
      (const float*)d_in[6],  (const float*)d_in[7],  (const float*)d_in[8],
      (const float*)d_in[9],  (const float*)d_in[10], (const float*)d_in[11],
      (const float*)d_in[12], (const float*)d_in[13], (const float*)d_in[14],
      (const int*)d_in[16],
      (float*)d_out, Bv, ns);
}

// Round 13
// 2901.463 us; speedup vs baseline: 1.0384x; 1.0007x over previous
//
#include <hip/hip_runtime.h>
#include <math.h>

// Problem constants (fixed by the reference)
constexpr int N_ = 101, H_ = 128;
constexpr float EPS_ = 1e-5f;

// Dynamic LDS layout (float words) — 27,512 words = 110,048 B
constexpr int OFF_QEF = 0;                    // 101x128: QEF = EF'@wq'
constexpr int OFF_KT  = 12928;                // 101x129 (13032): staging Kp/EF', then K
constexpr int OFF_AT  = 25960;                // 816: attn weights (8 x 101); setup: pool partials
constexpr int OFF_XV  = 26776;                // 144: x (padded-36 chunks)
constexpr int OFF_YR  = 26920;                // 144: y raw (padded-36 chunks)
constexpr int OFF_CP  = 27064;                // 128: comp (setup: pool_proc)
constexpr int OFF_RS  = 27192;                // 320: efsum[104], efs2[104], effc[104], scalars@312
constexpr int LDS_WORDS = 27512;
constexpr int LDS_BYTES = LDS_WORDS * 4;

__device__ __forceinline__ float rdlane(float v, int l) {
  return __int_as_float(__builtin_amdgcn_readlane(__float_as_int(v), l));
}
// DPP reductions (verified r12)
template<int CTRL, int RM>
__device__ __forceinline__ float dppadd(float x) {
  int v = __builtin_amdgcn_update_dpp(0, __float_as_int(x), CTRL, RM, 0xf, true);
  return x + __int_as_float(v);
}
template<int CTRL, int RM>
__device__ __forceinline__ float dppmax(float x) {
  int v = __builtin_amdgcn_update_dpp(__float_as_int(x), __float_as_int(x), CTRL, RM, 0xf, false);
  return fmaxf(x, __int_as_float(v));
}
__device__ __forceinline__ float wave_sum(float x) {
  x = dppadd<0x111,0xf>(x); x = dppadd<0x112,0xf>(x);
  x = dppadd<0x114,0xf>(x); x = dppadd<0x118,0xf>(x);
  x = dppadd<0x142,0xa>(x); x = dppadd<0x143,0xc>(x);
  return rdlane(x, 63);
}
__device__ __forceinline__ float wave_max(float x) {
  x = dppmax<0x111,0xf>(x); x = dppmax<0x112,0xf>(x);
  x = dppmax<0x114,0xf>(x); x = dppmax<0x118,0xf>(x);
  x = dppmax<0x142,0xa>(x); x = dppmax<0x143,0xc>(x);
  return rdlane(x, 63);
}
__device__ __forceinline__ float grp4_sum(float x) {   // valid at lane 4c+3
  x = dppadd<0x111,0xf>(x);
  x = dppadd<0x112,0xf>(x);
  return x;
}
__device__ __forceinline__ int swz(int k) { return (k >> 5) * 36 + (k & 31); }

__global__ __launch_bounds__(512, 2) void gat_decoder(
    const float* __restrict__ enc, const float* __restrict__ pool,
    const float* __restrict__ capac, const float* __restrict__ dem,
    const float* __restrict__ fcw, const float* __restrict__ fc1w,
    const float* __restrict__ lng, const float* __restrict__ lnb,
    const float* __restrict__ wq, const float* __restrict__ wk,
    const float* __restrict__ wvm, const float* __restrict__ wo,
    const float* __restrict__ kpw, const float* __restrict__ plg,
    const float* __restrict__ plb, const int* __restrict__ tp,
    float* __restrict__ out, int Bv, int ns)
{
  extern __shared__ float sm[];
  const int tid  = threadIdx.x;
  const int b    = blockIdx.x;
  const int lane = tid & 63;
  const int wvid = tid >> 6;        // wave id 0..7 (= head id)
  const int sl   = lane & 3;        // k-slice (adjacent lanes -> 2-hop DPP)
  const int lc   = lane >> 2;       // local column 0..15
  const int col  = wvid * 16 + lc;  // output column owned by this thread
  const int n1 = lane, n2 = lane + 64;

  const float NEG_INF = -__builtin_inff();
  int ti = tp[0];
  float Tf = (ti > 1000000 || ti < -1000000) ? __int_as_float((int)ti) : (float)ti;
  const float inv_sqrt_h = 1.0f / sqrtf(128.0f);
  const float PSUM_CONST = 1.0f + (float)N_ * 1e-10f;

  const float* encb = enc + (size_t)b * (N_ * H_);

  float* QEF = sm + OFF_QEF; float* KT = sm + OFF_KT;
  float* AT = sm + OFF_AT;   float* XVp = sm + OFF_XV;
  float* YRp = sm + OFF_YR;  float* CP = sm + OFF_CP;
  float* RS = sm + OFF_RS;

  const int j3 = tid & 127;
  const int g3 = __builtin_amdgcn_readfirstlane(tid >> 7);
  const int r03 = g3 * 26, nr3 = (g3 == 3) ? 23 : 26;

  // ===== P0: pool partials -> AT ; Kp -> KT =====
  {
    const float* pb = pool + (size_t)b * H_;
    float p = 0.f;
    #pragma unroll
    for (int r = 0; r < 32; ++r) p = fmaf(pb[g3 * 32 + r], fc1w[(g3 * 32 + r) * H_ + j3], p);
    AT[g3 * 128 + j3] = p;
  }
  {
    float acc[26];
    #pragma unroll
    for (int t = 0; t < 26; ++t) acc[t] = 0.f;
    for (int k0 = 0; k0 < H_; k0 += 8) {
      float w8[8];
      #pragma unroll
      for (int kk = 0; kk < 8; ++kk) w8[kk] = kpw[(k0 + kk) * H_ + j3];
      #pragma unroll
      for (int t = 0; t < 26; ++t) if (t < nr3) {
        const float* ep = encb + (r03 + t) * H_ + k0;
        #pragma unroll
        for (int kk = 0; kk < 8; ++kk) acc[t] = fmaf(ep[kk], w8[kk], acc[t]);
      }
    }
    #pragma unroll
    for (int t = 0; t < 26; ++t) if (t < nr3) KT[(r03 + t) * 129 + j3] = acc[t];
  }
  __syncthreads();

  // ===== P1: pool_proc -> CP ; kpT extract + pointer-LN fold =====
  if (tid < 128) CP[tid] = AT[tid] + AT[128 + tid] + AT[256 + tid] + AT[384 + tid];
  float kpT[32], kps, cpb;
  {
    const int neff = (col < N_) ? col : (N_ - 1);
    const float* src = KT + neff * 129 + sl * 32;
    float ks = 0.f, cb = 0.f;
    #pragma unroll
    for (int r = 0; r < 32; ++r) {
      const float kv = src[r];
      const float pg = plg[sl * 32 + r];
      const float pb2 = plb[sl * 32 + r];
      ks = fmaf(kv, pg, ks);
      cb = fmaf(kv, pb2, cb);
      kpT[r] = kv * pg;
    }
    kps = grp4_sum(ks); cpb = grp4_sum(cb);
  }
  __syncthreads();

  // ===== P2: EF' = enc@fc_w + pool_proc -> KT =====
  {
    const float pcj = CP[j3];
    float acc[26];
    #pragma unroll
    for (int t = 0; t < 26; ++t) acc[t] = pcj;
    for (int k0 = 0; k0 < H_; k0 += 8) {
      float w8[8];
      #pragma unroll
      for (int kk = 0; kk < 8; ++kk) w8[kk] = fcw[(k0 + kk) * H_ + j3];
      #pragma unroll
      for (int t = 0; t < 26; ++t) if (t < nr3) {
        const float* ep = encb + (r03 + t) * H_ + k0;
        #pragma unroll
        for (int kk = 0; kk < 8; ++kk) acc[t] = fmaf(ep[kk], w8[kk], acc[t]);
      }
    }
    #pragma unroll
    for (int t = 0; t < 26; ++t) if (t < nr3) KT[(r03 + t) * 129 + j3] = acc[t];
  }
  __syncthreads();

  // ===== P3: QEF = EF'@wq' ; row stats -> RS =====
  {
    float qacc[26];
    #pragma unroll
    for (int t = 0; t < 26; ++t) qacc[t] = 0.f;
    for (int k0 = 0; k0 < H_; k0 += 8) {
      float w8[8];
      #pragma unroll
      for (int kk = 0; kk < 8; ++kk) w8[kk] = wq[(k0 + kk) * H_ + j3] * lng[k0 + kk];
      #pragma unroll
      for (int t = 0; t < 26; ++t) if (t < nr3) {
        const float* erow = KT + (r03 + t) * 129 + k0;   // LDS broadcast
        #pragma unroll
        for (int kk = 0; kk < 8; ++kk) qacc[t] = fmaf(erow[kk], w8[kk], qacc[t]);
      }
    }
    #pragma unroll
    for (int t = 0; t < 26; ++t) if (t < nr3) QEF[(r03 + t) * 128 + j3] = qacc[t];
  }
  if (tid < N_) {
    const float* base = KT + tid * 129;
    float s = 0.f, s2 = 0.f, sf = 0.f, fs = 0.f, fs2 = 0.f;
    for (int r = 0; r < 128; ++r) {
      const float v = base[r];
      const float fr = fcw[128 * H_ + r];
      s += v; s2 = fmaf(v, v, s2); sf = fmaf(v, fr, sf);
      fs += fr; fs2 = fmaf(fr, fr, fs2);
    }
    RS[tid] = s; RS[104 + tid] = s2; RS[208 + tid] = sf;
    if (tid == 0) { RS[312] = fs; RS[313] = fs2; }
  }
  __syncthreads();

  // ===== P4: K -> KT (overwrite EF') ; per-thread reg tables =====
  {
    float acc[26];
    #pragma unroll
    for (int t = 0; t < 26; ++t) acc[t] = 0.f;
    for (int k0 = 0; k0 < H_; k0 += 8) {
      float w8[8];
      #pragma unroll
      for (int kk = 0; kk < 8; ++kk) w8[kk] = wk[(k0 + kk) * H_ + j3];
      #pragma unroll
      for (int t = 0; t < 26; ++t) if (t < nr3) {
        const float* ep = encb + (r03 + t) * H_ + k0;
        #pragma unroll
        for (int kk = 0; kk < 8; ++kk) acc[t] = fmaf(ep[kk], w8[kk], acc[t]);
      }
    }
    #pragma unroll
    for (int t = 0; t < 26; ++t) if (t < nr3) KT[(r03 + t) * 129 + j3] = acc[t];
  }
  // V col-slices: vh[t] = V[sl*26+t][col]
  float vh[26];
  {
    const int r0v = sl * 26, nrv = (sl == 3) ? 23 : 26;
    #pragma unroll
    for (int t = 0; t < 26; ++t) vh[t] = 0.f;
    for (int k0 = 0; k0 < H_; k0 += 8) {
      float w8[8];
      #pragma unroll
      for (int kk = 0; kk < 8; ++kk) w8[kk] = wvm[(k0 + kk) * H_ + col];
      #pragma unroll
      for (int t = 0; t < 26; ++t) if (t < nrv) {
        const float* ep = encb + (r0v + t) * H_ + k0;
        #pragma unroll
        for (int kk = 0; kk < 8; ++kk) vh[t] = fmaf(ep[kk], w8[kk], vh[t]);
      }
    }
  }
  // wo rows for this thread's (sl, col)
  float wo_r[32];
  #pragma unroll
  for (int r = 0; r < 32; ++r) wo_r[r] = wo[(sl * 32 + r) * H_ + col];
  // per-col folded scalars: wqs, qb, wfc
  float wqs = 0.f, qb = 0.f, wfc = 0.f;
  for (int r = 0; r < 128; ++r) {
    const float w = wq[r * H_ + col];
    const float lg = lng[r], lb = lnb[r], fr = fcw[128 * H_ + r];
    wqs = fmaf(w, lg, wqs);
    qb  = fmaf(w, lb, qb);
    wfc = fmaf(w * lg, fr, wfc);
  }
  // per-wave redundant decode state
  const float capv = capac[b];
  float cap = capv, lpsum = 0.f;
  float demA = dem[(size_t)b * N_ + n1];
  float demC = (n2 < N_) ? dem[(size_t)b * N_ + n2] : 0.f;
  int vis = 0, pidx = 0;
  bool m1a = false, m1c = false, mbA, mbB;
  {
    bool infA = (n1 >= 1) && (demA > cap);
    bool infB = (n2 >= N_) || (demC > cap);
    bool feasA = (n1 >= 1) && !infA;
    bool feasB = (n2 < N_) && !infB;
    const bool anyf = __any(feasA || feasB);
    mbA = (n1 == 0) ? anyf : infA;
    mbB = infB;
  }
  __syncthreads();   // all tables ready
  const float fcsum = RS[312], fcs2 = RS[313];

  // ===== decode loop: 3 barriers/step, no global loads, no spill =====
  for (int i = 0; i < ns; ++i) {
    const int pu = __builtin_amdgcn_readfirstlane(pidx);

    // Q: folded stats + folded q; logits from LDS K; softmax; X
    {
      const float efsum = RS[pu], efs2 = RS[104 + pu], effc = RS[208 + pu];
      const float mu = (efsum + cap * fcsum) * (1.f / 128.f);
      const float msq = (efs2 + 2.f * cap * effc + cap * cap * fcs2) * (1.f / 128.f);
      const float inv = 1.0f / sqrtf(msq - mu * mu + EPS_);
      const float qefv = QEF[pu * 128 + col];
      const float q = inv * (qefv + cap * wfc - mu * wqs) + qb;
      // logits: q of head cols via readlane (quad-lane 4d holds col d of this wave's head)
      const float* kb1 = KT + n1 * 129 + wvid * 16;
      const float* kb2 = KT + ((n2 < N_) ? n2 : n1) * 129 + wvid * 16;
      float a1 = 0.f, a2r = 0.f;
      #pragma unroll
      for (int d = 0; d < 16; ++d) {
        const float qdv = rdlane(q, 4 * d);
        a1  = fmaf(qdv, kb1[d], a1);
        a2r = fmaf(qdv, kb2[d], a2r);
      }
      a1 = mbA ? NEG_INF : a1 * 0.25f;
      float a2 = (n2 < N_ && !mbB) ? a2r * 0.25f : NEG_INF;
      const float mx = wave_max(fmaxf(a1, a2));
      float e1 = expf(a1 - mx);
      float e2 = (n2 < N_) ? expf(a2 - mx) : 0.f;
      const float ss = wave_sum(e1 + e2);
      AT[wvid * N_ + n1] = e1 / ss;
      if (n2 < N_) AT[wvid * N_ + n2] = e2 / ss;
      // X: x[col] = attn(head) @ V — same-wave AT reads
      const float* aw = AT + wvid * N_ + sl * 26;
      const int nrv = (sl == 3) ? 23 : 26;
      float x = 0.f;
      #pragma unroll
      for (int t = 0; t < 26; ++t) if (t < nrv) x = fmaf(aw[t], vh[t], x);
      x = grp4_sum(x);
      if (sl == 3) XVp[swz(col)] = x;
    }
    __syncthreads();                                            // bar1

    // Y: y[col] = x @ wo  (padded-36 chunks -> conflict-free b128)
    {
      const float4* xp4 = (const float4*)(XVp + sl * 36);
      float y = 0.f;
      #pragma unroll
      for (int r4 = 0; r4 < 8; ++r4) {
        const float4 u = xp4[r4];
        y = fmaf(wo_r[r4 * 4 + 0], u.x, y);
        y = fmaf(wo_r[r4 * 4 + 1], u.y, y);
        y = fmaf(wo_r[r4 * 4 + 2], u.z, y);
        y = fmaf(wo_r[r4 * 4 + 3], u.w, y);
      }
      y = grp4_sum(y);
      if (sl == 3) YRp[swz(col)] = y;
    }
    __syncthreads();                                            // bar2

    // C: LN stats (DPP) || folded comp matvec with kpT'
    {
      const float YA = YRp[swz(n1)], YC = YRp[swz(n2 & 127)];
      const float mu = wave_sum(YA + YC) * (1.f / 128.f);
      const float da = YA - mu, dc = YC - mu;
      const float inv = 1.0f / sqrtf(wave_sum(da * da + dc * dc) * (1.f / 128.f) + EPS_);
      const float4* yp4 = (const float4*)(YRp + sl * 36);
      float c = 0.f;
      #pragma unroll
      for (int r4 = 0; r4 < 8; ++r4) {
        const float4 u = yp4[r4];
        c = fmaf(kpT[r4 * 4 + 0], u.x, c);
        c = fmaf(kpT[r4 * 4 + 1], u.y, c);
        c = fmaf(kpT[r4 * 4 + 2], u.z, c);
        c = fmaf(kpT[r4 * 4 + 3], u.w, c);
      }
      c = grp4_sum(c);
      const float comp = inv * (c - mu * kps) + cpb;
      if (sl == 3 && col < N_) CP[col] = comp;
    }
    __syncthreads();                                            // bar3

    // AM — all waves redundantly
    {
      const bool allmb = __all(mbA && mbB);
      float c1 = mbA ? NEG_INF : CP[n1] * inv_sqrt_h / Tf;
      float c2 = (n2 < N_ && !mbB) ? CP[n2 & 127] * inv_sqrt_h / Tf : NEG_INF;
      if (allmb) { c1 = 0.f; c2 = (n2 < N_) ? 0.f : NEG_INF; }
      const float mx = wave_max(fmaxf(c1, c2));
      const unsigned long long b1 = __ballot(c1 == mx);
      const unsigned long long b2 = __ballot(c2 == mx);
      const int bis = b1 ? (__ffsll((long long)b1) - 1)
                         : (64 + __ffsll((long long)b2) - 1);
      float e1 = expf(c1 - mx);
      float e2 = (n2 < N_) ? expf(c2 - mx) : 0.f;
      const float ss = wave_sum(e1 + e2);
      float lp = logf((1.0f / ss + 1e-10f) / PSUM_CONST);
      if (vis >= N_ - 1) lp = 0.f;
      lpsum += lp;
      const float dsel = (bis < 64) ? rdlane(demA, bis) : rdlane(demC, bis - 64);
      cap = (bis == 0) ? capv : (cap - dsel);
      if (bis != 0) {
        const bool newly = ((bis == n1) && !m1a) || ((bis == n2) && !m1c);
        if (__any(newly)) vis += 1;
        m1a = m1a || (bis == n1);
        m1c = m1c || (bis == n2);
      }
      bool infA = (n1 >= 1) && (m1a || demA > cap);
      bool infB = (n2 >= N_) || m1c || (demC > cap);
      bool feasA = (n1 >= 1) && !infA;
      bool feasB = (n2 < N_) && !infB;
      const bool anyf = __any(feasA || feasB);
      const bool depot_m = anyf && (bis == 0);
      mbA = (n1 == 0) ? depot_m : infA;
      mbB = infB;
      pidx = bis;
      if (wvid == 0 && lane == 0) out[(size_t)b * (ns + 2) + 1 + i] = (float)bis;
    }
    // hazards: next Q writes AT (same-wave) and XVp (last read in Y, 2 barriers back). safe.
  }

  if (wvid == 0 && lane == 0) {
    out[(size_t)b * (ns + 2)] = 0.f;
    out[(size_t)b * (ns + 2) + ns + 1] = (pidx == 0) ? -1.f : 0.f;
    out[(size_t)Bv * (ns + 2) + b] = lpsum;   // log_p
  }
}

extern "C" void kernel_launch(void* const* d_in, const int* in_sizes, int n_in,
                              void* d_out, int out_size, void* d_ws, size_t ws_size,
                              hipStream_t stream) {
  const int Bv = in_sizes[0] / (N_ * H_);   // 1024
  const int ns = out_size / Bv - 3;         // 120
  (void)hipFuncSetAttribute(reinterpret_cast<const void*>(gat_decoder),
                            hipFuncAttributeMaxDynamicSharedMemorySize, LDS_BYTES);
  gat_decoder<<<dim3(Bv), dim3(512), LDS_BYTES, stream>>>(
      (const float*)d_in[0],  (const float*)d_in[1],  (const float*)d_in[2],
      (const float*)d_in[3],  (const float*)d_in[4],  (const float*)d_in[5],
      (const float*)d_in[6],  (const float*)d_in[7],  (const float*)d_in[8],
      (const float*)d_in[9],  (const float*)d_in[10], (const float*)d_in[11],
      (const float*)d_in[12], (const float*)d_in[13], (const float*)d_in[14],
      (const int*)d_in[16],
      (float*)d_out, Bv, ns);
}